// Round 6
// baseline (48.696 us; speedup 1.0000x reference)
//
#include <hip/hip_runtime.h>

// Sinusoidal oscillator with FM: out[b,n] = sin(2*pi * exclusive_cumsum_n(f0_rev*(1+mod_env*amt)))
// R6: wavefront-pipelined scan (decoupled lookback within the block) — ZERO steady-state
//     barriers. Wave w at chunk c polls LDS slot for predecessor's running total,
//     adds its wave total, publishes, then sins+stores. Waves self-timed -> load/store
//     bursts desynchronize instead of the whole GPU alternating in lockstep.
//     Dense per-wave layout from R5 (lane stride 16B). f32 element math, f64 chain.

constexpr int BLOCK = 1024;        // one block per row, 16 waves
constexpr int VPT   = 8;           // elems per thread per chunk
constexpr int NW    = BLOCK / 64;  // 16 waves
constexpr int WELEM = 64 * VPT;    // 512 elems per wave per chunk
constexpr int MAXCH = 16;          // max chunks (N=65536 -> 8 used)

typedef float f32x4 __attribute__((ext_vector_type(4)));

__global__ __launch_bounds__(BLOCK) void osc_kernel(
    const float* __restrict__ freq,        // [B]
    const float* __restrict__ mod_env,     // [B, N]
    const float* __restrict__ mod_amount,  // [B]
    float* __restrict__ out,               // [B, N]
    int N)
{
    const int row  = blockIdx.x;
    const int tid  = threadIdx.x;
    const int lane = tid & 63;
    const int wid  = tid >> 6;

    __shared__ double s_tot[MAXCH][NW];   // published running totals (rev)
    __shared__ int    s_flag[MAXCH][NW];  // 1 = slot published

    // Init flags once; the ONLY barrier in the kernel.
    for (int i = tid; i < MAXCH * NW; i += BLOCK) ((int*)s_flag)[i] = 0;
    __syncthreads();

    const double f0rev = (20.0 + 1980.0 * (double)freq[row]) / 48000.0;  // rev/sample
    const double amt   = -1.0 + 3.0 * (double)mod_amount[row];
    const float  kf    = (float)(f0rev * amt);
    const float  f0f   = (float)f0rev;

    const int chunk  = BLOCK * VPT;       // 8192
    const int nchunk = N / chunk;         // 8

    // Dense per-wave pointers: lane stride 16B within the wave's contiguous span
    const float* __restrict__ wload  = mod_env + (size_t)row * N + wid * WELEM + 4 * lane;
    float*       __restrict__ wstore = out     + (size_t)row * N + wid * WELEM + 4 * lane;

    // Prefetch chunk 0: two dense spans (base, base+256)
    f32x4 curA = *(const f32x4*)(wload);
    f32x4 curB = *(const f32x4*)(wload + 256);

    for (int c = 0; c < nchunk; ++c) {
        f32x4 nxtA = curA, nxtB = curB;
        if (c + 1 < nchunk) {
            const float* p = wload + (size_t)(c + 1) * chunk;
            nxtA = *(const f32x4*)(p);
            nxtB = *(const f32x4*)(p + 256);
        }

        // f32 per-element increments
        float va0 = fmaf(curA.x, kf, f0f), va1 = fmaf(curA.y, kf, f0f);
        float va2 = fmaf(curA.z, kf, f0f), va3 = fmaf(curA.w, kf, f0f);
        float vb0 = fmaf(curB.x, kf, f0f), vb1 = fmaf(curB.y, kf, f0f);
        float vb2 = fmaf(curB.z, kf, f0f), vb3 = fmaf(curB.w, kf, f0f);

        float sa = (va0 + va1) + (va2 + va3);
        float sb = (vb0 + vb1) + (vb2 + vb3);

        // Two interleaved f64 wave scans (span0 sums, span1 sums)
        double xa = (double)sa, xb = (double)sb;
        #pragma unroll
        for (int off = 1; off < 64; off <<= 1) {
            double ya = __shfl_up(xa, off, 64);
            double yb = __shfl_up(xb, off, 64);
            if (lane >= off) { xa += ya; xb += yb; }
        }
        double Ta = __shfl(xa, 63, 64);        // span0 wave total
        double T  = __shfl(xa + xb, 63, 64);   // full wave total

        // ---- decoupled lookback: get running total E before this wave ----
        double E = 0.0;
        if (!(c == 0 && wid == 0)) {
            const int pc = (wid == 0) ? c - 1 : c;
            const int pw = (wid == 0) ? NW - 1 : wid - 1;
            while (__hip_atomic_load(&s_flag[pc][pw], __ATOMIC_ACQUIRE,
                                     __HIP_MEMORY_SCOPE_WORKGROUP) == 0) {
                __builtin_amdgcn_s_sleep(1);
            }
            E = s_tot[pc][pw];
        }
        if (lane == 0) {
            s_tot[c][wid] = E + T;
            __hip_atomic_store(&s_flag[c][wid], 1, __ATOMIC_RELEASE,
                               __HIP_MEMORY_SCOPE_WORKGROUP);
        }
        // ------------------------------------------------------------------

        // Exclusive phase bases (revolutions) for the two spans
        double ph0 = E + (xa - (double)sa);
        double ph1 = E + Ta + (xb - (double)sb);

        float bf0 = (float)(ph0 - floor(ph0));
        float bf1 = (float)(ph1 - floor(ph1));

        f32x4 oA, oB;
        {
            float pf, fr;
            pf = bf0;
            fr = pf - floorf(pf); oA.x = __builtin_amdgcn_sinf(fr); pf += va0;
            fr = pf - floorf(pf); oA.y = __builtin_amdgcn_sinf(fr); pf += va1;
            fr = pf - floorf(pf); oA.z = __builtin_amdgcn_sinf(fr); pf += va2;
            fr = pf - floorf(pf); oA.w = __builtin_amdgcn_sinf(fr);
            pf = bf1;
            fr = pf - floorf(pf); oB.x = __builtin_amdgcn_sinf(fr); pf += vb0;
            fr = pf - floorf(pf); oB.y = __builtin_amdgcn_sinf(fr); pf += vb1;
            fr = pf - floorf(pf); oB.z = __builtin_amdgcn_sinf(fr); pf += vb2;
            fr = pf - floorf(pf); oB.w = __builtin_amdgcn_sinf(fr);
        }

        // Dense stores
        float* q = wstore + (size_t)c * chunk;
        *(f32x4*)(q)       = oA;
        *(f32x4*)(q + 256) = oB;

        curA = nxtA; curB = nxtB;
    }
}

extern "C" void kernel_launch(void* const* d_in, const int* in_sizes, int n_in,
                              void* d_out, int out_size, void* d_ws, size_t ws_size,
                              hipStream_t stream) {
    const float* freq       = (const float*)d_in[1];
    const float* mod_env    = (const float*)d_in[2];
    const float* mod_amount = (const float*)d_in[3];
    float* out = (float*)d_out;

    const int B = in_sizes[1];              // 512
    const int N = in_sizes[2] / B;          // 65536

    osc_kernel<<<B, BLOCK, 0, stream>>>(freq, mod_env, mod_amount, out, N);
}

// Round 7
// 45.808 us; speedup vs baseline: 1.0631x; 1.0631x over previous
//
#include <hip/hip_runtime.h>

// Sinusoidal oscillator with FM: out[b,n] = sin(exclusive_cumsum_n(f0_rev*(1+mod_env*amt)) * 2*pi)
// Computed in revolutions; phase scan in f64; hardware v_sin_f32 (input in revolutions).
// FINAL: revert to the measured-best R1 structure (45.8 us). Subsequent experiments
// (NT stores, f32 element math, dense per-wave layout, barrier-free lookback scan)
// were all neutral or negative; kernel runs at ~91% of the 6.29 TB/s mixed-stream
// copy ceiling with irreducible 262 MB instruction-level traffic.

constexpr int BLOCK = 1024;   // threads per block (one block per row)
constexpr int VPT   = 8;      // values per thread per chunk

__global__ __launch_bounds__(BLOCK) void osc_kernel(
    const float* __restrict__ freq,        // [B]
    const float* __restrict__ mod_env,     // [B, N]
    const float* __restrict__ mod_amount,  // [B]
    float* __restrict__ out,               // [B, N]
    int N)
{
    const int row  = blockIdx.x;
    const int tid  = threadIdx.x;
    const int lane = tid & 63;
    const int wid  = tid >> 6;            // wave id, 0..15

    __shared__ double s_wsum[BLOCK / 64];
    __shared__ double s_woff[BLOCK / 64 + 1];   // exclusive wave offsets; [nw] = chunk total

    // Per-row constants (f64, matching a float64 numpy reference)
    const double f0rev = (20.0 + 1980.0 * (double)freq[row]) / 48000.0;  // rev/sample
    const double amt   = -1.0 + 3.0 * (double)mod_amount[row];
    const double k     = f0rev * amt;     // freq_env_rev = f0rev + me * k

    const float* __restrict__ rowp = mod_env + (size_t)row * N;
    float* __restrict__ outp       = out     + (size_t)row * N;

    const int chunk  = BLOCK * VPT;       // 8192
    const int nchunk = N / chunk;         // N = 65536 -> 8

    double carry = 0.0;

    // Prefetch chunk 0
    const float* p0 = rowp + tid * VPT;
    float4 curA = *(const float4*)(p0);
    float4 curB = *(const float4*)(p0 + 4);

    for (int c = 0; c < nchunk; ++c) {
        // Prefetch next chunk while we compute this one
        float4 nxtA = curA, nxtB = curB;
        if (c + 1 < nchunk) {
            const float* p = rowp + (size_t)(c + 1) * chunk + tid * VPT;
            nxtA = *(const float4*)(p);
            nxtB = *(const float4*)(p + 4);
        }

        // Per-element increments (rev/sample) in f64
        double v0 = fma((double)curA.x, k, f0rev);
        double v1 = fma((double)curA.y, k, f0rev);
        double v2 = fma((double)curA.z, k, f0rev);
        double v3 = fma((double)curA.w, k, f0rev);
        double v4 = fma((double)curB.x, k, f0rev);
        double v5 = fma((double)curB.y, k, f0rev);
        double v6 = fma((double)curB.z, k, f0rev);
        double v7 = fma((double)curB.w, k, f0rev);

        double tsum = ((v0 + v1) + (v2 + v3)) + ((v4 + v5) + (v6 + v7));

        // Wave-level inclusive scan of per-thread sums (f64)
        double x = tsum;
        #pragma unroll
        for (int off = 1; off < 64; off <<= 1) {
            double y = __shfl_up(x, off, 64);
            if (lane >= off) x += y;
        }

        if (lane == 63) s_wsum[wid] = x;
        __syncthreads();

        // Cross-wave scan (16 wave sums) by the first 16 lanes of wave 0
        if (tid < BLOCK / 64) {
            double w  = s_wsum[tid];
            double xs = w;
            #pragma unroll
            for (int off = 1; off < BLOCK / 64; off <<= 1) {
                double y = __shfl_up(xs, off, 64);
                if (tid >= off) xs += y;
            }
            s_woff[tid] = xs - w;                       // exclusive
            if (tid == BLOCK / 64 - 1) s_woff[BLOCK / 64] = xs;  // total
        }
        __syncthreads();

        // Exclusive phase base for this thread (revolutions)
        double phase = carry + s_woff[wid] + (x - tsum);

        float4 oA, oB;
        {
            double pf;
            pf = phase - floor(phase); oA.x = __builtin_amdgcn_sinf((float)pf); phase += v0;
            pf = phase - floor(phase); oA.y = __builtin_amdgcn_sinf((float)pf); phase += v1;
            pf = phase - floor(phase); oA.z = __builtin_amdgcn_sinf((float)pf); phase += v2;
            pf = phase - floor(phase); oA.w = __builtin_amdgcn_sinf((float)pf); phase += v3;
            pf = phase - floor(phase); oB.x = __builtin_amdgcn_sinf((float)pf); phase += v4;
            pf = phase - floor(phase); oB.y = __builtin_amdgcn_sinf((float)pf); phase += v5;
            pf = phase - floor(phase); oB.z = __builtin_amdgcn_sinf((float)pf); phase += v6;
            pf = phase - floor(phase); oB.w = __builtin_amdgcn_sinf((float)pf); phase += v7;
        }

        float* q = outp + (size_t)c * chunk + tid * VPT;
        *(float4*)(q)     = oA;
        *(float4*)(q + 4) = oB;

        carry += s_woff[BLOCK / 64];
        __syncthreads();   // protect s_wsum/s_woff before next chunk overwrites

        curA = nxtA; curB = nxtB;
    }
}

extern "C" void kernel_launch(void* const* d_in, const int* in_sizes, int n_in,
                              void* d_out, int out_size, void* d_ws, size_t ws_size,
                              hipStream_t stream) {
    const float* freq       = (const float*)d_in[1];
    const float* mod_env    = (const float*)d_in[2];
    const float* mod_amount = (const float*)d_in[3];
    float* out = (float*)d_out;

    const int B = in_sizes[1];              // 512
    const int N = in_sizes[2] / B;          // 65536

    osc_kernel<<<B, BLOCK, 0, stream>>>(freq, mod_env, mod_amount, out, N);
}